// Round 8
// baseline (540.906 us; speedup 1.0000x reference)
//
#include <hip/hip_runtime.h>
#include <math.h>

// Problem constants: B=8, C=128, H=W=64, NC=64, NH=4, HC=16, KS=4,
// Hk=Wk=16, Ns=256, HW=4096, NB=3 blocks: (i,j) = (1,0),(2,0),(2,1)

typedef _Float16 f16x4 __attribute__((ext_vector_type(4)));
typedef float f32x4 __attribute__((ext_vector_type(4)));

// ---------------------------------------------------------------- copy out=x
__global__ __launch_bounds__(256) void k_copy(
    const float* __restrict__ x0, const float* __restrict__ x1,
    const float* __restrict__ x2, float* __restrict__ out) {
  int i = blockIdx.x * 256 + threadIdx.x;       // float4 index, 3*1048576 total
  int lvl = i >> 20;
  int idx = i & 1048575;
  const float4* src = (lvl == 0) ? (const float4*)x0
                    : (lvl == 1) ? (const float4*)x1 : (const float4*)x2;
  ((float4*)out)[i] = src[idx];
}

// ------------------------------------------------- q = pq_w @ x_i[:, :64] + b
// og-split 8 (grid 3072, acc[8]) — round-6/7 occupancy lever.
__global__ __launch_bounds__(256) void k_qconv(
    const float* __restrict__ x1, const float* __restrict__ x2,
    const float* __restrict__ pq_w, const float* __restrict__ pq_b,
    float* __restrict__ q_buf) {
  int wg = blockIdx.x;            // num(3)<<10 | og(8)<<7 | b(8)<<4 | tile(16)
  int tile = wg & 15;
  int b = (wg >> 4) & 7;
  int og = (wg >> 7) & 7;
  int num = wg >> 10;
  const float* xin = (num == 0) ? x1 : x2;
  int px = tile * 256 + threadIdx.x;
  const float* xbase = xin + b * 524288 + px;   // channels 0..63 used
  const float* w = pq_w + num * 4096 + og * 512;  // rows og*8..og*8+7
  float acc[8];
#pragma unroll
  for (int o = 0; o < 8; ++o) acc[o] = 0.f;
#pragma unroll 8
  for (int c = 0; c < 64; ++c) {
    float xv = xbase[c * 4096];                 // coalesced, 8 in flight
#pragma unroll
    for (int o = 0; o < 8; ++o) acc[o] += w[o * 64 + c] * xv;  // s_loads
  }
  float* qb = q_buf + ((num * 8 + b) * 64 + og * 8) * 4096 + px;
  const float* bias = pq_b + num * 64 + og * 8;
#pragma unroll
  for (int o = 0; o < 8; ++o) qb[o * 4096] = acc[o] + bias[o];
}

// ---------------- offset head: depthwise 4x4 s4 + LN + GELU + proj -> pos
// Round-8: was 24 blocks (24 of 256 CUs!) with a 64-deep serial erf chain.
// Now 96 blocks; 4 lanes (tid^16, tid^32 groups) split the 64 channels,
// LN stats and proj sums reduced via width-4 __shfl_xor. Per-thread
// serial chain 64 -> 16 erf evaluations.
__global__ __launch_bounds__(256) void k_offset(
    const float* __restrict__ q_buf, const float* __restrict__ dw_w,
    const float* __restrict__ dw_b, const float* __restrict__ ln_g,
    const float* __restrict__ ln_b, const float* __restrict__ pw_w,
    float* __restrict__ pos_buf) {
  int wg = blockIdx.x;            // 96 = nb(24) * ptile(4)
  int ptile = wg & 3;
  int nb = wg >> 2;               // num*8+b
  int num = nb >> 3;
  int tid = threadIdx.x;
  int pix_lo = tid & 15;
  int cg = (tid >> 4) & 3;        // channel group; partners at tid^16, tid^32
  int pix_hi = tid >> 6;
  int n = ptile * 64 + pix_hi * 16 + pix_lo;    // offset-grid pixel 0..255
  int oy = n >> 4, ox = n & 15;
  const float* qb = q_buf + nb * 64 * 4096;
  float off_r[16];
  float sum = 0.f, sumsq = 0.f;
#pragma unroll
  for (int cc = 0; cc < 16; ++cc) {
    int c = cg * 16 + cc;
    const float* wp = dw_w + (num * 64 + c) * 16;
    const float* qp = qb + c * 4096 + oy * 256 + ox * 4;
    float4 r0 = *(const float4*)(qp);
    float4 r1 = *(const float4*)(qp + 64);
    float4 r2 = *(const float4*)(qp + 128);
    float4 r3 = *(const float4*)(qp + 192);
    float s = dw_b[num * 64 + c];
    s += wp[0] * r0.x + wp[1] * r0.y + wp[2] * r0.z + wp[3] * r0.w;
    s += wp[4] * r1.x + wp[5] * r1.y + wp[6] * r1.z + wp[7] * r1.w;
    s += wp[8] * r2.x + wp[9] * r2.y + wp[10] * r2.z + wp[11] * r2.w;
    s += wp[12] * r3.x + wp[13] * r3.y + wp[14] * r3.z + wp[15] * r3.w;
    off_r[cc] = s;
    sum += s;
    sumsq += s * s;
  }
  sum += __shfl_xor(sum, 16);   sum += __shfl_xor(sum, 32);
  sumsq += __shfl_xor(sumsq, 16); sumsq += __shfl_xor(sumsq, 32);
  float mu = sum * 0.015625f;
  float var = sumsq * 0.015625f - mu * mu;
  float rstd = rsqrtf(var + 1e-5f);
  float offy = 0.f, offx = 0.f;
#pragma unroll
  for (int cc = 0; cc < 16; ++cc) {
    int c = cg * 16 + cc;
    float g = (off_r[cc] - mu) * rstd * ln_g[num * 64 + c] + ln_b[num * 64 + c];
    g = 0.5f * g * (1.f + erff(g * 0.70710678118654752f));  // exact gelu
    offy += pw_w[num * 128 + c] * g;
    offx += pw_w[num * 128 + 64 + c] * g;
  }
  offy += __shfl_xor(offy, 16); offy += __shfl_xor(offy, 32);
  offx += __shfl_xor(offx, 16); offx += __shfl_xor(offx, 32);
  if (cg == 0) {
    float ref_y = (0.5f + (float)oy) * (2.f / 15.f) - 1.f;
    float ref_x = (0.5f + (float)ox) * (2.f / 15.f) - 1.f;
    float py = fminf(fmaxf(offy + ref_y, -1.f), 1.f);
    float px = fminf(fmaxf(offx + ref_x, -1.f), 1.f);
    pos_buf[(nb * 256 + n) * 2 + 0] = py;
    pos_buf[(nb * 256 + n) * 2 + 1] = px;
  }
}

// ------------- bilinear sample kv (align_corners=True) -> xs[num][b][c][n]
// Round-8: cg split 8 -> 16 (grid 384) so all CUs are covered.
__global__ __launch_bounds__(256) void k_sample(
    const float* __restrict__ x0, const float* __restrict__ x1,
    const float* __restrict__ pos_buf, float* __restrict__ xs_buf) {
  int wg = blockIdx.x;
  int cg = wg & 15;
  int b = (wg >> 4) & 7;
  int num = wg >> 7;
  const float* xj = (num == 2) ? x1 : x0;       // kv source: x0,x0,x1
  int n = threadIdx.x;
  int nb = num * 8 + b;
  float py = pos_buf[(nb * 256 + n) * 2 + 0];
  float px = pos_buf[(nb * 256 + n) * 2 + 1];
  float fy = (py + 1.f) * 31.5f;                // (g+1)*0.5*(64-1)
  float fx = (px + 1.f) * 31.5f;
  float y0f = floorf(fy), x0f = floorf(fx);
  float wy = fy - y0f, wx = fx - x0f;
  int y0 = (int)y0f, xi0 = (int)x0f;
  int y1 = min(y0 + 1, 63), xi1 = min(xi0 + 1, 63);  // OOB tap has weight 0
  float w00 = (1.f - wy) * (1.f - wx), w01 = (1.f - wy) * wx;
  float w10 = wy * (1.f - wx), w11 = wy * wx;
  const float* xb = xj + b * 524288;
#pragma unroll
  for (int cc = 0; cc < 4; ++cc) {
    int c = cg * 4 + cc;
    const float* p = xb + c * 4096;
    float v = w00 * p[y0 * 64 + xi0] + w01 * p[y0 * 64 + xi1] +
              w10 * p[y1 * 64 + xi0] + w11 * p[y1 * 64 + xi1];
    xs_buf[(nb * 64 + c) * 256 + n] = v;
  }
}

// -------------------------------- k = pk_w@xs + pk_b ; v = pv_w@xs + pv_b
// og-split 8 (grid 384), f16 output (cvt moved here from k_attn).
__global__ __launch_bounds__(256) void k_kv(
    const float* __restrict__ xs_buf, const float* __restrict__ pk_w,
    const float* __restrict__ pk_b, const float* __restrict__ pv_w,
    const float* __restrict__ pv_b, _Float16* __restrict__ k16,
    _Float16* __restrict__ v16) {
  int wg = blockIdx.x;              // 384 = og(8) * nb(24) * which(2)
  int which = wg & 1;
  int rest = wg >> 1;
  int nb = rest % 24;
  int og = rest / 24;
  int num = nb >> 3;
  const float* w = (which ? pv_w : pk_w) + num * 4096 + og * 512;
  const float* bias = (which ? pv_b : pk_b) + num * 64 + og * 8;
  _Float16* ob = (which ? v16 : k16) + (nb * 64 + og * 8) * 256;
  const float* xsb = xs_buf + nb * 64 * 256;
  int n = threadIdx.x;
  float acc[8];
#pragma unroll
  for (int o = 0; o < 8; ++o) acc[o] = 0.f;
#pragma unroll 8
  for (int c = 0; c < 64; ++c) {
    float xv = xsb[c * 256 + n];
#pragma unroll
    for (int o = 0; o < 8; ++o) acc[o] += w[o * 64 + c] * xv;
  }
#pragma unroll
  for (int o = 0; o < 8; ++o) ob[o * 256 + n] = (_Float16)(acc[o] + bias[o]);
}

// -------- pad rpe tables 127x127 -> 128x128 (dup last row/col).
// NOTE: tpad ALIASES xs_buf (dead after k_kv); ws footprint unchanged.
__global__ __launch_bounds__(128) void k_padrpe(
    const float* __restrict__ rpe, float* __restrict__ tpad) {
  int wg = blockIdx.x;              // 12 tables * 128 rows
  int tbl = wg >> 7;
  int r = wg & 127;
  int c = threadIdx.x;
  int rs = min(r, 126), cs = min(c, 126);
  tpad[tbl * 16384 + r * 128 + c] = rpe[tbl * 16129 + rs * 127 + cs];
}

// ----------------- MFMA attention. S^T = K_A . Q_B  (16x16x16 f16):
// C-layout of S^T (n=quad*4+reg, m=lane&15) == B-frag layout for PV
// (O^T = V_A . P^T_B), so no transpose round-trip is needed.
// grid 1536 = num(3)*b(8)*h(4)*mblock(16); 4 waves, each 4 m-tiles of 16.
//
// Round-8 changes (occupancy 32%, conflicts 1.12e7, LDS 39.9KB -> only 4
// of the 6 blocks/CU resident -> ragged 2-generation schedule):
//  * bias table stored in F16: LDS 22,528 B -> all 6 blocks/CU resident.
//    rpe ~N(0,0.1): f16 tap error ~5e-5 on logits, far below tolerance.
//    Each 16-lane tap run now covers 8 banks (2 lanes share a dword ->
//    broadcast, free) -> cross-quad collisions roughly halve.
//  * log2(e) folded into precomputed weights -> exp is a bare v_exp_f32.
__global__ __launch_bounds__(256) void k_attn(
    float* __restrict__ q_buf, const _Float16* __restrict__ k16,
    const _Float16* __restrict__ v16, const float* __restrict__ pos_buf,
    const float* __restrict__ tpad) {
  int wg = blockIdx.x;
  int mblock = wg & 15;
  int h = (wg >> 4) & 3;
  int b = (wg >> 6) & 7;
  int num = wg >> 9;
  int nb = num * 8 + b;
  int tid = threadIdx.x;
  int lane = tid & 63;
  int wave = __builtin_amdgcn_readfirstlane(tid >> 6);
  int l15 = lane & 15;
  int quad = lane >> 4;

  __shared__ __align__(16) _Float16 s_T[68 * 128];  // 17,408 B
  __shared__ float4 s_wt[256];                      //  4,096 B
  __shared__ int s_off[256];                        //  1,024 B (22,528 total)

  // stage + f32->f16 convert the block's table window: rows mblock*4 ..
  // mblock*4+67 (68x128 = 8704 floats = 2176 float4).
  {
    const float4* Ts = (const float4*)(tpad + (num * 4 + h) * 16384 + mblock * 512);
    f16x4* Td = (f16x4*)s_T;
#pragma unroll
    for (int i = 0; i < 8; ++i) {
      float4 v = Ts[tid + i * 256];
      f16x4 hv;
      hv[0] = (_Float16)v.x; hv[1] = (_Float16)v.y;
      hv[2] = (_Float16)v.z; hv[3] = (_Float16)v.w;
      Td[tid + i * 256] = hv;
    }
    if (tid < 128) {
      float4 v = Ts[tid + 2048];              // 2176 = 8.5*256
      f16x4 hv;
      hv[0] = (_Float16)v.x; hv[1] = (_Float16)v.y;
      hv[2] = (_Float16)v.z; hv[3] = (_Float16)v.w;
      Td[tid + 2048] = hv;
    }
  }

  // per-key bilinear params: table coord t = m + 31.5*(1-pos).
  // Tap offset + 4 bilinear weights, weights PRE-SCALED by log2(e).
  {
    float py = pos_buf[(nb * 256 + tid) * 2 + 0];
    float px = pos_buf[(nb * 256 + tid) * 2 + 1];
    float by = 31.5f * (1.f - py);
    float bx = 31.5f * (1.f - px);
    float iyf = floorf(by), ixf = floorf(bx);
    float wy = by - iyf, wx = bx - ixf;
    float uy = 1.f - wy, ux = 1.f - wx;
    const float L2E = 1.44269504088896341f;
    s_off[tid] = (int)iyf * 128 + (int)ixf;
    s_wt[tid] = make_float4(uy * ux * L2E, uy * wx * L2E,
                            wy * ux * L2E, wy * wx * L2E);
  }
  __syncthreads();

  int hc = nb * 64 + h * 16;
  const _Float16* kb = k16 + hc * 256;
  const _Float16* vb = v16 + hc * 256;
  float* qb = q_buf + hc * 4096;
  const _Float16* Trow = s_T + wave * 128 + l15;   // + mt*16 + tap offset

  // persistent per-mt state (statically indexed everywhere)
  f16x4 qf[4];
  f32x4 O[4];
  float L[4];
#pragma unroll
  for (int mt = 0; mt < 4; ++mt) {
    int m = mblock * 256 + wave * 64 + mt * 16 + l15;
#pragma unroll
    for (int j = 0; j < 4; ++j)
      qf[mt][j] = (_Float16)qb[(quad * 4 + j) * 4096 + m];  // B[c][m]
    O[mt][0] = 0.f; O[mt][1] = 0.f; O[mt][2] = 0.f; O[mt][3] = 0.f;
    L[mt] = 0.f;
  }

#pragma unroll 2
  for (int t = 0; t < 16; ++t) {
    // K frag: A[n][c]: n = t*16 + l15, c = quad*4+j  (f16 direct loads)
    f16x4 kf;
#pragma unroll
    for (int j = 0; j < 4; ++j)
      kf[j] = kb[(quad * 4 + j) * 256 + t * 16 + l15];
    // V frag: A[c][n]: c = l15, n = t*16 + quad*4+j -> contiguous 8B f16x4
    f16x4 vf = *(const f16x4*)(vb + l15 * 256 + t * 16 + quad * 4);

    f32x4 S[4];
#pragma unroll
    for (int mt = 0; mt < 4; ++mt) {
      f32x4 Z = {0.f, 0.f, 0.f, 0.f};
      S[mt] = __builtin_amdgcn_mfma_f32_16x16x16f16(kf, qf[mt], Z, 0, 0, 0);
    }

    f16x4 pf[4];
#pragma unroll
    for (int r = 0; r < 4; ++r) {
      int off = s_off[t * 16 + quad * 4 + r];     // broadcast b32
      float4 wt = s_wt[t * 16 + quad * 4 + r];    // broadcast b128
#pragma unroll
      for (int mt = 0; mt < 4; ++mt) {
        const _Float16* p = Trow + mt * 16 + off;
        float bias = wt.x * (float)p[0] + wt.y * (float)p[1] +
                     wt.z * (float)p[128] + wt.w * (float)p[129];
        // 0.25 * log2(e); bias already in log2 domain
        float s = fmaf(S[mt][r], 0.36067376022224085f, bias);
        float e = __builtin_amdgcn_exp2f(s);
        L[mt] += e;
        pf[mt][r] = (_Float16)e;
      }
    }
#pragma unroll
    for (int mt = 0; mt < 4; ++mt)
      O[mt] = __builtin_amdgcn_mfma_f32_16x16x16f16(vf, pf[mt], O[mt], 0, 0, 0);
  }

#pragma unroll
  for (int mt = 0; mt < 4; ++mt) {
    float Lm = L[mt];
    Lm += __shfl_xor(Lm, 16);
    Lm += __shfl_xor(Lm, 32);
    float rinv = 1.f / Lm;
    int m = mblock * 256 + wave * 64 + mt * 16 + l15;
#pragma unroll
    for (int r = 0; r < 4; ++r)
      qb[(quad * 4 + r) * 4096 + m] = O[mt][r] * rinv;  // in-place over q
  }
}

// ------------------- po conv, out[l][b][64+o][p] += sum_num conv + bias
// og-split 8 (grid 2048, acc[8]); level-2 blocks loop num in {1,2}.
__global__ __launch_bounds__(256) void k_po(
    const float* __restrict__ attn_buf, const float* __restrict__ po_w,
    const float* __restrict__ po_b, float* __restrict__ out) {
  int wg = blockIdx.x;              // l(2)<<10 | og(8)<<7 | b(8)<<4 | tile(16)
  int tile = wg & 15;
  int b = (wg >> 4) & 7;
  int og = (wg >> 7) & 7;
  int l = (wg >> 10) + 1;           // 1 or 2
  int px = tile * 256 + threadIdx.x;
  int nlo = (l == 1) ? 0 : 1;
  int nPasses = (l == 1) ? 1 : 2;

  float acc[8];
#pragma unroll
  for (int o = 0; o < 8; ++o) acc[o] = 0.f;

  for (int s = 0; s < nPasses; ++s) {
    int num = nlo + s;
    const float* abase = attn_buf + (num * 8 + b) * 64 * 4096 + px;
    const float* w = po_w + num * 4096 + og * 512;
#pragma unroll 8
    for (int c = 0; c < 64; ++c) {
      float xv = abase[c * 4096];   // coalesced, 8 in flight
#pragma unroll
      for (int o = 0; o < 8; ++o) acc[o] += w[o * 64 + c] * xv;  // s_loads
    }
  }

  float* ob = out + ((l * 8 + b) * 128 + 64 + og * 8) * 4096 + px;
#pragma unroll
  for (int o = 0; o < 8; ++o) {
    float bias = po_b[nlo * 64 + og * 8 + o];
    if (l == 2) bias += po_b[128 + og * 8 + o];
    ob[o * 4096] += acc[o] + bias;  // plain RMW, no atomics
  }
}

extern "C" void kernel_launch(void* const* d_in, const int* in_sizes, int n_in,
                              void* d_out, int out_size, void* d_ws,
                              size_t ws_size, hipStream_t stream) {
  const float* x0 = (const float*)d_in[0];
  const float* x1 = (const float*)d_in[1];
  const float* x2 = (const float*)d_in[2];
  const float* pq_w = (const float*)d_in[3];
  const float* pq_b = (const float*)d_in[4];
  const float* dw_w = (const float*)d_in[5];
  const float* dw_b = (const float*)d_in[6];
  const float* ln_g = (const float*)d_in[7];
  const float* ln_b = (const float*)d_in[8];
  const float* pw_w = (const float*)d_in[9];
  const float* pk_w = (const float*)d_in[10];
  const float* pk_b = (const float*)d_in[11];
  const float* pv_w = (const float*)d_in[12];
  const float* pv_b = (const float*)d_in[13];
  const float* po_w = (const float*)d_in[14];
  const float* po_b = (const float*)d_in[15];
  const float* rpe = (const float*)d_in[16];
  float* out = (float*)d_out;
  float* ws = (float*)d_ws;

  // ws layout (floats): q/attn (in-place) 6291456, pos 12288, xs 393216,
  // k 393216, v 393216 -> 29,933,568 bytes, IDENTICAL to round-0-proven size.
  // tpad (196608) aliases xs_buf: xs is dead after k_kv; k_padrpe runs after.
  // k/v buffers hold f16 (half the region used; offsets unchanged).
  float* q_buf = ws;
  float* pos_buf = q_buf + 6291456;
  float* xs_buf = pos_buf + 12288;
  float* k_buf = xs_buf + 393216;
  float* v_buf = k_buf + 393216;
  float* tpad = xs_buf;
  _Float16* k16 = (_Float16*)k_buf;
  _Float16* v16 = (_Float16*)v_buf;

  hipLaunchKernelGGL(k_copy, dim3(12288), dim3(256), 0, stream, x0, x1, x2, out);
  hipLaunchKernelGGL(k_qconv, dim3(3072), dim3(256), 0, stream, x1, x2, pq_w,
                     pq_b, q_buf);
  hipLaunchKernelGGL(k_offset, dim3(96), dim3(256), 0, stream, q_buf, dw_w,
                     dw_b, ln_g, ln_b, pw_w, pos_buf);
  hipLaunchKernelGGL(k_sample, dim3(384), dim3(256), 0, stream, x0, x1,
                     pos_buf, xs_buf);
  hipLaunchKernelGGL(k_kv, dim3(384), dim3(256), 0, stream, xs_buf, pk_w, pk_b,
                     pv_w, pv_b, k16, v16);
  hipLaunchKernelGGL(k_padrpe, dim3(1536), dim3(128), 0, stream, rpe, tpad);
  hipLaunchKernelGGL(k_attn, dim3(1536), dim3(256), 0, stream, q_buf, k16,
                     v16, pos_buf, tpad);
  hipLaunchKernelGGL(k_po, dim3(2048), dim3(256), 0, stream, q_buf, po_w, po_b,
                     out);
}

// Round 9
// 258.285 us; speedup vs baseline: 2.0942x; 2.0942x over previous
//
#include <hip/hip_runtime.h>
#include <math.h>

// Problem constants: B=8, C=128, H=W=64, NC=64, NH=4, HC=16, KS=4,
// Hk=Wk=16, Ns=256, HW=4096, NB=3 blocks: (i,j) = (1,0),(2,0),(2,1)

typedef _Float16 f16x4 __attribute__((ext_vector_type(4)));
typedef _Float16 f16x2 __attribute__((ext_vector_type(2)));
typedef float f32x4 __attribute__((ext_vector_type(4)));

// ---------------------------------------------------------------- copy out=x
__global__ __launch_bounds__(256) void k_copy(
    const float* __restrict__ x0, const float* __restrict__ x1,
    const float* __restrict__ x2, float* __restrict__ out) {
  int i = blockIdx.x * 256 + threadIdx.x;       // float4 index, 3*1048576 total
  int lvl = i >> 20;
  int idx = i & 1048575;
  const float4* src = (lvl == 0) ? (const float4*)x0
                    : (lvl == 1) ? (const float4*)x1 : (const float4*)x2;
  ((float4*)out)[i] = src[idx];
}

// ------------------------------------------------- q = pq_w @ x_i[:, :64] + b
// og-split 8 (grid 3072, acc[8]) — round-6/7 occupancy lever.
__global__ __launch_bounds__(256) void k_qconv(
    const float* __restrict__ x1, const float* __restrict__ x2,
    const float* __restrict__ pq_w, const float* __restrict__ pq_b,
    float* __restrict__ q_buf) {
  int wg = blockIdx.x;            // num(3)<<10 | og(8)<<7 | b(8)<<4 | tile(16)
  int tile = wg & 15;
  int b = (wg >> 4) & 7;
  int og = (wg >> 7) & 7;
  int num = wg >> 10;
  const float* xin = (num == 0) ? x1 : x2;
  int px = tile * 256 + threadIdx.x;
  const float* xbase = xin + b * 524288 + px;   // channels 0..63 used
  const float* w = pq_w + num * 4096 + og * 512;  // rows og*8..og*8+7
  float acc[8];
#pragma unroll
  for (int o = 0; o < 8; ++o) acc[o] = 0.f;
#pragma unroll 8
  for (int c = 0; c < 64; ++c) {
    float xv = xbase[c * 4096];                 // coalesced, 8 in flight
#pragma unroll
    for (int o = 0; o < 8; ++o) acc[o] += w[o * 64 + c] * xv;  // s_loads
  }
  float* qb = q_buf + ((num * 8 + b) * 64 + og * 8) * 4096 + px;
  const float* bias = pq_b + num * 64 + og * 8;
#pragma unroll
  for (int o = 0; o < 8; ++o) qb[o * 4096] = acc[o] + bias[o];
}

// ---------------- offset head: depthwise 4x4 s4 + LN + GELU + proj -> pos
// 96 blocks; 4 lanes (tid^16, tid^32 groups) split the 64 channels,
// LN stats and proj sums reduced via width-4 __shfl_xor.
__global__ __launch_bounds__(256) void k_offset(
    const float* __restrict__ q_buf, const float* __restrict__ dw_w,
    const float* __restrict__ dw_b, const float* __restrict__ ln_g,
    const float* __restrict__ ln_b, const float* __restrict__ pw_w,
    float* __restrict__ pos_buf) {
  int wg = blockIdx.x;            // 96 = nb(24) * ptile(4)
  int ptile = wg & 3;
  int nb = wg >> 2;               // num*8+b
  int num = nb >> 3;
  int tid = threadIdx.x;
  int pix_lo = tid & 15;
  int cg = (tid >> 4) & 3;        // channel group; partners at tid^16, tid^32
  int pix_hi = tid >> 6;
  int n = ptile * 64 + pix_hi * 16 + pix_lo;    // offset-grid pixel 0..255
  int oy = n >> 4, ox = n & 15;
  const float* qb = q_buf + nb * 64 * 4096;
  float off_r[16];
  float sum = 0.f, sumsq = 0.f;
#pragma unroll
  for (int cc = 0; cc < 16; ++cc) {
    int c = cg * 16 + cc;
    const float* wp = dw_w + (num * 64 + c) * 16;
    const float* qp = qb + c * 4096 + oy * 256 + ox * 4;
    float4 r0 = *(const float4*)(qp);
    float4 r1 = *(const float4*)(qp + 64);
    float4 r2 = *(const float4*)(qp + 128);
    float4 r3 = *(const float4*)(qp + 192);
    float s = dw_b[num * 64 + c];
    s += wp[0] * r0.x + wp[1] * r0.y + wp[2] * r0.z + wp[3] * r0.w;
    s += wp[4] * r1.x + wp[5] * r1.y + wp[6] * r1.z + wp[7] * r1.w;
    s += wp[8] * r2.x + wp[9] * r2.y + wp[10] * r2.z + wp[11] * r2.w;
    s += wp[12] * r3.x + wp[13] * r3.y + wp[14] * r3.z + wp[15] * r3.w;
    off_r[cc] = s;
    sum += s;
    sumsq += s * s;
  }
  sum += __shfl_xor(sum, 16);   sum += __shfl_xor(sum, 32);
  sumsq += __shfl_xor(sumsq, 16); sumsq += __shfl_xor(sumsq, 32);
  float mu = sum * 0.015625f;
  float var = sumsq * 0.015625f - mu * mu;
  float rstd = rsqrtf(var + 1e-5f);
  float offy = 0.f, offx = 0.f;
#pragma unroll
  for (int cc = 0; cc < 16; ++cc) {
    int c = cg * 16 + cc;
    float g = (off_r[cc] - mu) * rstd * ln_g[num * 64 + c] + ln_b[num * 64 + c];
    g = 0.5f * g * (1.f + erff(g * 0.70710678118654752f));  // exact gelu
    offy += pw_w[num * 128 + c] * g;
    offx += pw_w[num * 128 + 64 + c] * g;
  }
  offy += __shfl_xor(offy, 16); offy += __shfl_xor(offy, 32);
  offx += __shfl_xor(offx, 16); offx += __shfl_xor(offx, 32);
  if (cg == 0) {
    float ref_y = (0.5f + (float)oy) * (2.f / 15.f) - 1.f;
    float ref_x = (0.5f + (float)ox) * (2.f / 15.f) - 1.f;
    float py = fminf(fmaxf(offy + ref_y, -1.f), 1.f);
    float px = fminf(fmaxf(offx + ref_x, -1.f), 1.f);
    pos_buf[(nb * 256 + n) * 2 + 0] = py;
    pos_buf[(nb * 256 + n) * 2 + 1] = px;
  }
}

// ------------- bilinear sample kv (align_corners=True) -> xs[num][b][c][n]
__global__ __launch_bounds__(256) void k_sample(
    const float* __restrict__ x0, const float* __restrict__ x1,
    const float* __restrict__ pos_buf, float* __restrict__ xs_buf) {
  int wg = blockIdx.x;
  int cg = wg & 15;
  int b = (wg >> 4) & 7;
  int num = wg >> 7;
  const float* xj = (num == 2) ? x1 : x0;       // kv source: x0,x0,x1
  int n = threadIdx.x;
  int nb = num * 8 + b;
  float py = pos_buf[(nb * 256 + n) * 2 + 0];
  float px = pos_buf[(nb * 256 + n) * 2 + 1];
  float fy = (py + 1.f) * 31.5f;                // (g+1)*0.5*(64-1)
  float fx = (px + 1.f) * 31.5f;
  float y0f = floorf(fy), x0f = floorf(fx);
  float wy = fy - y0f, wx = fx - x0f;
  int y0 = (int)y0f, xi0 = (int)x0f;
  int y1 = min(y0 + 1, 63), xi1 = min(xi0 + 1, 63);  // OOB tap has weight 0
  float w00 = (1.f - wy) * (1.f - wx), w01 = (1.f - wy) * wx;
  float w10 = wy * (1.f - wx), w11 = wy * wx;
  const float* xb = xj + b * 524288;
#pragma unroll
  for (int cc = 0; cc < 4; ++cc) {
    int c = cg * 4 + cc;
    const float* p = xb + c * 4096;
    float v = w00 * p[y0 * 64 + xi0] + w01 * p[y0 * 64 + xi1] +
              w10 * p[y1 * 64 + xi0] + w11 * p[y1 * 64 + xi1];
    xs_buf[(nb * 64 + c) * 256 + n] = v;
  }
}

// -------------------------------- k = pk_w@xs + pk_b ; v = pv_w@xs + pv_b
// og-split 8 (grid 384), f16 output (cvt moved here from k_attn).
__global__ __launch_bounds__(256) void k_kv(
    const float* __restrict__ xs_buf, const float* __restrict__ pk_w,
    const float* __restrict__ pk_b, const float* __restrict__ pv_w,
    const float* __restrict__ pv_b, _Float16* __restrict__ k16,
    _Float16* __restrict__ v16) {
  int wg = blockIdx.x;              // 384 = og(8) * nb(24) * which(2)
  int which = wg & 1;
  int rest = wg >> 1;
  int nb = rest % 24;
  int og = rest / 24;
  int num = nb >> 3;
  const float* w = (which ? pv_w : pk_w) + num * 4096 + og * 512;
  const float* bias = (which ? pv_b : pk_b) + num * 64 + og * 8;
  _Float16* ob = (which ? v16 : k16) + (nb * 64 + og * 8) * 256;
  const float* xsb = xs_buf + nb * 64 * 256;
  int n = threadIdx.x;
  float acc[8];
#pragma unroll
  for (int o = 0; o < 8; ++o) acc[o] = 0.f;
#pragma unroll 8
  for (int c = 0; c < 64; ++c) {
    float xv = xsb[c * 256 + n];
#pragma unroll
    for (int o = 0; o < 8; ++o) acc[o] += w[o * 64 + c] * xv;
  }
#pragma unroll
  for (int o = 0; o < 8; ++o) ob[o * 256 + n] = (_Float16)(acc[o] + bias[o]);
}

// -------- pad rpe tables 127x127 -> 128x128 (dup last row/col).
// NOTE: tpad ALIASES xs_buf (dead after k_kv); ws footprint unchanged.
__global__ __launch_bounds__(128) void k_padrpe(
    const float* __restrict__ rpe, float* __restrict__ tpad) {
  int wg = blockIdx.x;              // 12 tables * 128 rows
  int tbl = wg >> 7;
  int r = wg & 127;
  int c = threadIdx.x;
  int rs = min(r, 126), cs = min(c, 126);
  tpad[tbl * 16384 + r * 128 + c] = rpe[tbl * 16129 + rs * 127 + cs];
}

// ----------------- MFMA attention. S^T = K_A . Q_B  (16x16x16 f16):
// C-layout of S^T (n=quad*4+reg, m=lane&15) == B-frag layout for PV
// (O^T = V_A . P^T_B), so no transpose round-trip is needed.
// grid 1536 = num(3)*b(8)*h(4)*mblock(16); 4 waves, each 4 m-tiles of 16.
//
// Round-9 analysis: round-7 arithmetic shows k_attn is DS-ISSUE-bound
// (1152 DS instrs/thread x 24 wave-units/CU x ~5.8cyc = 67us = measured).
// Round-8's scalar _Float16 taps compiled to ds_read_u16_d16 (partial-
// register merges -> false deps -> serialized tap stream, 351us, VALUBusy
// 12%). Fix: HALF2 X-PAIR table. entry[r][c] = (T[r][c], T[r][c+1]) in one
// 32-bit word -> each tap group needs only TWO full-dword ds_read_b32
// (row, row+1), fresh destinations, no d16 merges. DS per r-iter 18 -> 10;
// DS floor ~40us. Table 34,816 B; LDS total 39,936 -> 4 blocks/CU kept.
// f16 tap precision already validated (round 8 passed, same absmax).
__global__ __launch_bounds__(256) void k_attn(
    float* __restrict__ q_buf, const _Float16* __restrict__ k16,
    const _Float16* __restrict__ v16, const float* __restrict__ pos_buf,
    const float* __restrict__ tpad) {
  int wg = blockIdx.x;
  int mblock = wg & 15;
  int h = (wg >> 4) & 3;
  int b = (wg >> 6) & 7;
  int num = wg >> 9;
  int nb = num * 8 + b;
  int tid = threadIdx.x;
  int lane = tid & 63;
  int wave = __builtin_amdgcn_readfirstlane(tid >> 6);
  int l15 = lane & 15;
  int quad = lane >> 4;

  __shared__ __align__(16) f16x2 s_P[68 * 128];   // 34,816 B (x-pair table)
  __shared__ float4 s_wt[256];                    //  4,096 B
  __shared__ int s_off[256];                      //  1,024 B (39,936 total)

  // stage the block's window (rows mblock*4 .. mblock*4+67, 68x128 floats)
  // as x-pairs: s_P[i] = (T[i], T[i+1]) packed half2. col 127 entries are
  // never read as a base (max base col = 126) -> dup is fine.
  {
    const float* Ts = tpad + (num * 4 + h) * 16384 + mblock * 512;
    for (int i = tid; i < 8704; i += 256) {
      float a = Ts[i];
      float bb = Ts[i + (((i & 127) < 127) ? 1 : 0)];
      f16x2 hv;
      hv[0] = (_Float16)a;
      hv[1] = (_Float16)bb;
      s_P[i] = hv;
    }
  }

  // per-key bilinear params: table coord t = m + 31.5*(1-pos).
  // Tap offset (entry units) + 4 bilinear weights PRE-SCALED by log2(e).
  {
    float py = pos_buf[(nb * 256 + tid) * 2 + 0];
    float px = pos_buf[(nb * 256 + tid) * 2 + 1];
    float by = 31.5f * (1.f - py);
    float bx = 31.5f * (1.f - px);
    float iyf = floorf(by), ixf = floorf(bx);
    float wy = by - iyf, wx = bx - ixf;
    float uy = 1.f - wy, ux = 1.f - wx;
    const float L2E = 1.44269504088896341f;
    s_off[tid] = (int)iyf * 128 + (int)ixf;
    s_wt[tid] = make_float4(uy * ux * L2E, uy * wx * L2E,
                            wy * ux * L2E, wy * wx * L2E);
  }
  __syncthreads();

  int hc = nb * 64 + h * 16;
  const _Float16* kb = k16 + hc * 256;
  const _Float16* vb = v16 + hc * 256;
  float* qb = q_buf + hc * 4096;
  const f16x2* Trow = s_P + wave * 128 + l15;   // + mt*16 + tap offset

  // persistent per-mt state (statically indexed everywhere)
  f16x4 qf[4];
  f32x4 O[4];
  float L[4];
#pragma unroll
  for (int mt = 0; mt < 4; ++mt) {
    int m = mblock * 256 + wave * 64 + mt * 16 + l15;
#pragma unroll
    for (int j = 0; j < 4; ++j)
      qf[mt][j] = (_Float16)qb[(quad * 4 + j) * 4096 + m];  // B[c][m]
    O[mt][0] = 0.f; O[mt][1] = 0.f; O[mt][2] = 0.f; O[mt][3] = 0.f;
    L[mt] = 0.f;
  }

#pragma unroll 2
  for (int t = 0; t < 16; ++t) {
    // K frag: A[n][c]: n = t*16 + l15, c = quad*4+j  (f16 direct loads)
    f16x4 kf;
#pragma unroll
    for (int j = 0; j < 4; ++j)
      kf[j] = kb[(quad * 4 + j) * 256 + t * 16 + l15];
    // V frag: A[c][n]: c = l15, n = t*16 + quad*4+j -> contiguous 8B f16x4
    f16x4 vf = *(const f16x4*)(vb + l15 * 256 + t * 16 + quad * 4);

    f32x4 S[4];
#pragma unroll
    for (int mt = 0; mt < 4; ++mt) {
      f32x4 Z = {0.f, 0.f, 0.f, 0.f};
      S[mt] = __builtin_amdgcn_mfma_f32_16x16x16f16(kf, qf[mt], Z, 0, 0, 0);
    }

    f16x4 pf[4];
#pragma unroll
    for (int r = 0; r < 4; ++r) {
      int off = s_off[t * 16 + quad * 4 + r];     // broadcast b32
      float4 wt = s_wt[t * 16 + quad * 4 + r];    // broadcast b128
#pragma unroll
      for (int mt = 0; mt < 4; ++mt) {
        const f16x2* p = Trow + mt * 16 + off;
        f16x2 t0 = p[0];                          // ds_read_b32 (row, x-pair)
        f16x2 t1 = p[128];                        // ds_read_b32 (row+1)
        float bias = wt.x * (float)t0[0] + wt.y * (float)t0[1] +
                     wt.z * (float)t1[0] + wt.w * (float)t1[1];
        // 0.25 * log2(e); bias already in log2 domain
        float s = fmaf(S[mt][r], 0.36067376022224085f, bias);
        float e = __builtin_amdgcn_exp2f(s);
        L[mt] += e;
        pf[mt][r] = (_Float16)e;
      }
    }
#pragma unroll
    for (int mt = 0; mt < 4; ++mt)
      O[mt] = __builtin_amdgcn_mfma_f32_16x16x16f16(vf, pf[mt], O[mt], 0, 0, 0);
  }

#pragma unroll
  for (int mt = 0; mt < 4; ++mt) {
    float Lm = L[mt];
    Lm += __shfl_xor(Lm, 16);
    Lm += __shfl_xor(Lm, 32);
    float rinv = 1.f / Lm;
    int m = mblock * 256 + wave * 64 + mt * 16 + l15;
#pragma unroll
    for (int r = 0; r < 4; ++r)
      qb[(quad * 4 + r) * 4096 + m] = O[mt][r] * rinv;  // in-place over q
  }
}

// ------------------- po conv, out[l][b][64+o][p] += sum_num conv + bias
// og-split 8 (grid 2048, acc[8]); level-2 blocks loop num in {1,2}.
__global__ __launch_bounds__(256) void k_po(
    const float* __restrict__ attn_buf, const float* __restrict__ po_w,
    const float* __restrict__ po_b, float* __restrict__ out) {
  int wg = blockIdx.x;              // l(2)<<10 | og(8)<<7 | b(8)<<4 | tile(16)
  int tile = wg & 15;
  int b = (wg >> 4) & 7;
  int og = (wg >> 7) & 7;
  int l = (wg >> 10) + 1;           // 1 or 2
  int px = tile * 256 + threadIdx.x;
  int nlo = (l == 1) ? 0 : 1;
  int nPasses = (l == 1) ? 1 : 2;

  float acc[8];
#pragma unroll
  for (int o = 0; o < 8; ++o) acc[o] = 0.f;

  for (int s = 0; s < nPasses; ++s) {
    int num = nlo + s;
    const float* abase = attn_buf + (num * 8 + b) * 64 * 4096 + px;
    const float* w = po_w + num * 4096 + og * 512;
#pragma unroll 8
    for (int c = 0; c < 64; ++c) {
      float xv = abase[c * 4096];   // coalesced, 8 in flight
#pragma unroll
      for (int o = 0; o < 8; ++o) acc[o] += w[o * 64 + c] * xv;  // s_loads
    }
  }

  float* ob = out + ((l * 8 + b) * 128 + 64 + og * 8) * 4096 + px;
#pragma unroll
  for (int o = 0; o < 8; ++o) {
    float bias = po_b[nlo * 64 + og * 8 + o];
    if (l == 2) bias += po_b[128 + og * 8 + o];
    ob[o * 4096] += acc[o] + bias;  // plain RMW, no atomics
  }
}

extern "C" void kernel_launch(void* const* d_in, const int* in_sizes, int n_in,
                              void* d_out, int out_size, void* d_ws,
                              size_t ws_size, hipStream_t stream) {
  const float* x0 = (const float*)d_in[0];
  const float* x1 = (const float*)d_in[1];
  const float* x2 = (const float*)d_in[2];
  const float* pq_w = (const float*)d_in[3];
  const float* pq_b = (const float*)d_in[4];
  const float* dw_w = (const float*)d_in[5];
  const float* dw_b = (const float*)d_in[6];
  const float* ln_g = (const float*)d_in[7];
  const float* ln_b = (const float*)d_in[8];
  const float* pw_w = (const float*)d_in[9];
  const float* pk_w = (const float*)d_in[10];
  const float* pk_b = (const float*)d_in[11];
  const float* pv_w = (const float*)d_in[12];
  const float* pv_b = (const float*)d_in[13];
  const float* po_w = (const float*)d_in[14];
  const float* po_b = (const float*)d_in[15];
  const float* rpe = (const float*)d_in[16];
  float* out = (float*)d_out;
  float* ws = (float*)d_ws;

  // ws layout (floats): q/attn (in-place) 6291456, pos 12288, xs 393216,
  // k 393216, v 393216 -> 29,933,568 bytes, IDENTICAL to round-0-proven size.
  // tpad (196608) aliases xs_buf: xs is dead after k_kv; k_padrpe runs after.
  // k/v buffers hold f16 (half the region used; offsets unchanged).
  float* q_buf = ws;
  float* pos_buf = q_buf + 6291456;
  float* xs_buf = pos_buf + 12288;
  float* k_buf = xs_buf + 393216;
  float* v_buf = k_buf + 393216;
  float* tpad = xs_buf;
  _Float16* k16 = (_Float16*)k_buf;
  _Float16* v16 = (_Float16*)v_buf;

  hipLaunchKernelGGL(k_copy, dim3(12288), dim3(256), 0, stream, x0, x1, x2, out);
  hipLaunchKernelGGL(k_qconv, dim3(3072), dim3(256), 0, stream, x1, x2, pq_w,
                     pq_b, q_buf);
  hipLaunchKernelGGL(k_offset, dim3(96), dim3(256), 0, stream, q_buf, dw_w,
                     dw_b, ln_g, ln_b, pw_w, pos_buf);
  hipLaunchKernelGGL(k_sample, dim3(384), dim3(256), 0, stream, x0, x1,
                     pos_buf, xs_buf);
  hipLaunchKernelGGL(k_kv, dim3(384), dim3(256), 0, stream, xs_buf, pk_w, pk_b,
                     pv_w, pv_b, k16, v16);
  hipLaunchKernelGGL(k_padrpe, dim3(1536), dim3(128), 0, stream, rpe, tpad);
  hipLaunchKernelGGL(k_attn, dim3(1536), dim3(256), 0, stream, q_buf, k16,
                     v16, pos_buf, tpad);
  hipLaunchKernelGGL(k_po, dim3(2048), dim3(256), 0, stream, q_buf, po_w, po_b,
                     out);
}

// Round 10
// 250.372 us; speedup vs baseline: 2.1604x; 1.0316x over previous
//
#include <hip/hip_runtime.h>
#include <math.h>

// Problem constants: B=8, C=128, H=W=64, NC=64, NH=4, HC=16, KS=4,
// Hk=Wk=16, Ns=256, HW=4096, NB=3 blocks: (i,j) = (1,0),(2,0),(2,1)

typedef _Float16 f16x8 __attribute__((ext_vector_type(8)));
typedef _Float16 f16x4 __attribute__((ext_vector_type(4)));
typedef _Float16 f16x2 __attribute__((ext_vector_type(2)));
typedef float f32x4 __attribute__((ext_vector_type(4)));

// ---------------------------------------------------------------- copy out=x
__global__ __launch_bounds__(256) void k_copy(
    const float* __restrict__ x0, const float* __restrict__ x1,
    const float* __restrict__ x2, float* __restrict__ out) {
  int i = blockIdx.x * 256 + threadIdx.x;       // float4 index, 3*1048576 total
  int lvl = i >> 20;
  int idx = i & 1048575;
  const float4* src = (lvl == 0) ? (const float4*)x0
                    : (lvl == 1) ? (const float4*)x1 : (const float4*)x2;
  ((float4*)out)[i] = src[idx];
}

// ------------------------------------------------- q = pq_w @ x_i[:, :64] + b
// og-split 8 (grid 3072, acc[8]) — round-6/7 occupancy lever.
__global__ __launch_bounds__(256) void k_qconv(
    const float* __restrict__ x1, const float* __restrict__ x2,
    const float* __restrict__ pq_w, const float* __restrict__ pq_b,
    float* __restrict__ q_buf) {
  int wg = blockIdx.x;            // num(3)<<10 | og(8)<<7 | b(8)<<4 | tile(16)
  int tile = wg & 15;
  int b = (wg >> 4) & 7;
  int og = (wg >> 7) & 7;
  int num = wg >> 10;
  const float* xin = (num == 0) ? x1 : x2;
  int px = tile * 256 + threadIdx.x;
  const float* xbase = xin + b * 524288 + px;   // channels 0..63 used
  const float* w = pq_w + num * 4096 + og * 512;  // rows og*8..og*8+7
  float acc[8];
#pragma unroll
  for (int o = 0; o < 8; ++o) acc[o] = 0.f;
#pragma unroll 8
  for (int c = 0; c < 64; ++c) {
    float xv = xbase[c * 4096];                 // coalesced, 8 in flight
#pragma unroll
    for (int o = 0; o < 8; ++o) acc[o] += w[o * 64 + c] * xv;  // s_loads
  }
  float* qb = q_buf + ((num * 8 + b) * 64 + og * 8) * 4096 + px;
  const float* bias = pq_b + num * 64 + og * 8;
#pragma unroll
  for (int o = 0; o < 8; ++o) qb[o * 4096] = acc[o] + bias[o];
}

// ---------------- offset head: depthwise 4x4 s4 + LN + GELU + proj -> pos
// 96 blocks; 4 lanes (tid^16, tid^32 groups) split the 64 channels,
// LN stats and proj sums reduced via width-4 __shfl_xor.
__global__ __launch_bounds__(256) void k_offset(
    const float* __restrict__ q_buf, const float* __restrict__ dw_w,
    const float* __restrict__ dw_b, const float* __restrict__ ln_g,
    const float* __restrict__ ln_b, const float* __restrict__ pw_w,
    float* __restrict__ pos_buf) {
  int wg = blockIdx.x;            // 96 = nb(24) * ptile(4)
  int ptile = wg & 3;
  int nb = wg >> 2;               // num*8+b
  int num = nb >> 3;
  int tid = threadIdx.x;
  int pix_lo = tid & 15;
  int cg = (tid >> 4) & 3;        // channel group; partners at tid^16, tid^32
  int pix_hi = tid >> 6;
  int n = ptile * 64 + pix_hi * 16 + pix_lo;    // offset-grid pixel 0..255
  int oy = n >> 4, ox = n & 15;
  const float* qb = q_buf + nb * 64 * 4096;
  float off_r[16];
  float sum = 0.f, sumsq = 0.f;
#pragma unroll
  for (int cc = 0; cc < 16; ++cc) {
    int c = cg * 16 + cc;
    const float* wp = dw_w + (num * 64 + c) * 16;
    const float* qp = qb + c * 4096 + oy * 256 + ox * 4;
    float4 r0 = *(const float4*)(qp);
    float4 r1 = *(const float4*)(qp + 64);
    float4 r2 = *(const float4*)(qp + 128);
    float4 r3 = *(const float4*)(qp + 192);
    float s = dw_b[num * 64 + c];
    s += wp[0] * r0.x + wp[1] * r0.y + wp[2] * r0.z + wp[3] * r0.w;
    s += wp[4] * r1.x + wp[5] * r1.y + wp[6] * r1.z + wp[7] * r1.w;
    s += wp[8] * r2.x + wp[9] * r2.y + wp[10] * r2.z + wp[11] * r2.w;
    s += wp[12] * r3.x + wp[13] * r3.y + wp[14] * r3.z + wp[15] * r3.w;
    off_r[cc] = s;
    sum += s;
    sumsq += s * s;
  }
  sum += __shfl_xor(sum, 16);   sum += __shfl_xor(sum, 32);
  sumsq += __shfl_xor(sumsq, 16); sumsq += __shfl_xor(sumsq, 32);
  float mu = sum * 0.015625f;
  float var = sumsq * 0.015625f - mu * mu;
  float rstd = rsqrtf(var + 1e-5f);
  float offy = 0.f, offx = 0.f;
#pragma unroll
  for (int cc = 0; cc < 16; ++cc) {
    int c = cg * 16 + cc;
    float g = (off_r[cc] - mu) * rstd * ln_g[num * 64 + c] + ln_b[num * 64 + c];
    g = 0.5f * g * (1.f + erff(g * 0.70710678118654752f));  // exact gelu
    offy += pw_w[num * 128 + c] * g;
    offx += pw_w[num * 128 + 64 + c] * g;
  }
  offy += __shfl_xor(offy, 16); offy += __shfl_xor(offy, 32);
  offx += __shfl_xor(offx, 16); offx += __shfl_xor(offx, 32);
  if (cg == 0) {
    float ref_y = (0.5f + (float)oy) * (2.f / 15.f) - 1.f;
    float ref_x = (0.5f + (float)ox) * (2.f / 15.f) - 1.f;
    float py = fminf(fmaxf(offy + ref_y, -1.f), 1.f);
    float px = fminf(fmaxf(offx + ref_x, -1.f), 1.f);
    pos_buf[(nb * 256 + n) * 2 + 0] = py;
    pos_buf[(nb * 256 + n) * 2 + 1] = px;
  }
}

// ------------- bilinear sample kv (align_corners=True) -> xs[num][b][c][n]
__global__ __launch_bounds__(256) void k_sample(
    const float* __restrict__ x0, const float* __restrict__ x1,
    const float* __restrict__ pos_buf, float* __restrict__ xs_buf) {
  int wg = blockIdx.x;
  int cg = wg & 15;
  int b = (wg >> 4) & 7;
  int num = wg >> 7;
  const float* xj = (num == 2) ? x1 : x0;       // kv source: x0,x0,x1
  int n = threadIdx.x;
  int nb = num * 8 + b;
  float py = pos_buf[(nb * 256 + n) * 2 + 0];
  float px = pos_buf[(nb * 256 + n) * 2 + 1];
  float fy = (py + 1.f) * 31.5f;                // (g+1)*0.5*(64-1)
  float fx = (px + 1.f) * 31.5f;
  float y0f = floorf(fy), x0f = floorf(fx);
  float wy = fy - y0f, wx = fx - x0f;
  int y0 = (int)y0f, xi0 = (int)x0f;
  int y1 = min(y0 + 1, 63), xi1 = min(xi0 + 1, 63);  // OOB tap has weight 0
  float w00 = (1.f - wy) * (1.f - wx), w01 = (1.f - wy) * wx;
  float w10 = wy * (1.f - wx), w11 = wy * wx;
  const float* xb = xj + b * 524288;
#pragma unroll
  for (int cc = 0; cc < 4; ++cc) {
    int c = cg * 4 + cc;
    const float* p = xb + c * 4096;
    float v = w00 * p[y0 * 64 + xi0] + w01 * p[y0 * 64 + xi1] +
              w10 * p[y1 * 64 + xi0] + w11 * p[y1 * 64 + xi1];
    xs_buf[(nb * 64 + c) * 256 + n] = v;
  }
}

// -------------------------------- k = pk_w@xs + pk_b ; v = pv_w@xs + pv_b
// og-split 8 (grid 384), f16 output. Round-10: K is written TRANSPOSED
// kT[nb][n][64] (one coalesced 16B f16x8 store per thread) so k_attn's
// K-fragment becomes a single 8B vector load instead of 4 scalar d16
// loads with false-dependency merges (round-8 pathology, global flavor).
__global__ __launch_bounds__(256) void k_kv(
    const float* __restrict__ xs_buf, const float* __restrict__ pk_w,
    const float* __restrict__ pk_b, const float* __restrict__ pv_w,
    const float* __restrict__ pv_b, _Float16* __restrict__ k16,
    _Float16* __restrict__ v16) {
  int wg = blockIdx.x;              // 384 = og(8) * nb(24) * which(2)
  int which = wg & 1;
  int rest = wg >> 1;
  int nb = rest % 24;
  int og = rest / 24;
  int num = nb >> 3;
  const float* w = (which ? pv_w : pk_w) + num * 4096 + og * 512;
  const float* bias = (which ? pv_b : pk_b) + num * 64 + og * 8;
  const float* xsb = xs_buf + nb * 64 * 256;
  int n = threadIdx.x;
  float acc[8];
#pragma unroll
  for (int o = 0; o < 8; ++o) acc[o] = 0.f;
#pragma unroll 8
  for (int c = 0; c < 64; ++c) {
    float xv = xsb[c * 256 + n];
#pragma unroll
    for (int o = 0; o < 8; ++o) acc[o] += w[o * 64 + c] * xv;
  }
  if (which) {                      // V: [nb][c][n], n contiguous
    _Float16* ob = v16 + (nb * 64 + og * 8) * 256 + n;
#pragma unroll
    for (int o = 0; o < 8; ++o) ob[o * 256] = (_Float16)(acc[o] + bias[o]);
  } else {                          // K^T: [nb][n][64], 16B store per thread
    f16x8 pack;
#pragma unroll
    for (int o = 0; o < 8; ++o) pack[o] = (_Float16)(acc[o] + bias[o]);
    *(f16x8*)(k16 + nb * 16384 + n * 64 + og * 8) = pack;
  }
}

// -------- pad rpe tables 127x127 -> 128x128 (dup last row/col).
// NOTE: tpad ALIASES xs_buf (dead after k_kv); ws footprint unchanged.
__global__ __launch_bounds__(128) void k_padrpe(
    const float* __restrict__ rpe, float* __restrict__ tpad) {
  int wg = blockIdx.x;              // 12 tables * 128 rows
  int tbl = wg >> 7;
  int r = wg & 127;
  int c = threadIdx.x;
  int rs = min(r, 126), cs = min(c, 126);
  tpad[tbl * 16384 + r * 128 + c] = rpe[tbl * 16129 + rs * 127 + cs];
}

// ----------------- MFMA attention. S^T = K_A . Q_B  (16x16x16 f16):
// C-layout of S^T (n=quad*4+reg, m=lane&15) == B-frag layout for PV
// (O^T = V_A . P^T_B), so no transpose round-trip is needed.
// grid 1536 = num(3)*b(8)*h(4)*mblock(16); 4 waves, each 4 m-tiles of 16.
//
// Round-10 (round-9 showed DS-halving alone left dur at 66.7us, VALUBusy
// 64% -> VALU-issue on the serial P-path is the binder; cut instructions
// on every axis):
//  * 0.25*log2(e) folded into the Q fragment at load (q_buf stays f32 for
//    k_offset) -> the per-P fmaf scale disappears; exp arg IS the dot acc.
//  * v_dot2_f32_f16: weights stored f16x4 (xL2E); per P = 2 dot2 + exp2 +
//    L-add + cvt (~5 VALU slots, was ~9). Weight read b128 -> b64.
//  * 8 x-pair taps per r batched from one base with const dword offsets
//    {0,16,32,48,128,144,160,176} -> compiler can merge to 4 ds_read2_b32
//    and batch the lgkmcnt wait.
//  * K fragment: single 8B load from transposed kT (no d16 merges).
// LDS 34,816 + 2,048 + 1,024 = 37,888 B -> 4 blocks/CU kept.
__global__ __launch_bounds__(256) void k_attn(
    float* __restrict__ q_buf, const _Float16* __restrict__ k16,
    const _Float16* __restrict__ v16, const float* __restrict__ pos_buf,
    const float* __restrict__ tpad) {
  int wg = blockIdx.x;
  int mblock = wg & 15;
  int h = (wg >> 4) & 3;
  int b = (wg >> 6) & 7;
  int num = wg >> 9;
  int nb = num * 8 + b;
  int tid = threadIdx.x;
  int lane = tid & 63;
  int wave = __builtin_amdgcn_readfirstlane(tid >> 6);
  int l15 = lane & 15;
  int quad = lane >> 4;

  __shared__ __align__(16) f16x2 s_P[68 * 128];   // 34,816 B (x-pair table)
  __shared__ f16x4 s_wt[256];                     //  2,048 B
  __shared__ int s_off[256];                      //  1,024 B (37,888 total)

  // stage the block's window (rows mblock*4 .. mblock*4+67, 68x128 floats)
  // as x-pairs: s_P[i] = (T[i], T[i+1]) packed half2. col 127 entries are
  // never read as a base (max base col = 126) -> dup is fine.
  {
    const float* Ts = tpad + (num * 4 + h) * 16384 + mblock * 512;
    for (int i = tid; i < 8704; i += 256) {
      float a = Ts[i];
      float bb = Ts[i + (((i & 127) < 127) ? 1 : 0)];
      f16x2 hv;
      hv[0] = (_Float16)a;
      hv[1] = (_Float16)bb;
      s_P[i] = hv;
    }
  }

  // per-key bilinear params: table coord t = m + 31.5*(1-pos).
  // Tap offset (entry units) + 4 bilinear weights f16, PRE-SCALED by log2e.
  {
    float py = pos_buf[(nb * 256 + tid) * 2 + 0];
    float px = pos_buf[(nb * 256 + tid) * 2 + 1];
    float by = 31.5f * (1.f - py);
    float bx = 31.5f * (1.f - px);
    float iyf = floorf(by), ixf = floorf(bx);
    float wy = by - iyf, wx = bx - ixf;
    float uy = 1.f - wy, ux = 1.f - wx;
    const float L2E = 1.44269504088896341f;
    s_off[tid] = (int)iyf * 128 + (int)ixf;
    f16x4 w4;
    w4[0] = (_Float16)(uy * ux * L2E);
    w4[1] = (_Float16)(uy * wx * L2E);
    w4[2] = (_Float16)(wy * ux * L2E);
    w4[3] = (_Float16)(wy * wx * L2E);
    s_wt[tid] = w4;
  }
  __syncthreads();

  int hc = nb * 64 + h * 16;
  const _Float16* kbT = k16 + nb * 16384;         // [n][64] transposed
  const _Float16* vb = v16 + hc * 256;            // [c][n]
  float* qb = q_buf + hc * 4096;
  const f16x2* Trow = s_P + wave * 128 + l15;     // + tap offset (+mt*16)

  // persistent per-mt state (statically indexed everywhere)
  f16x4 qf[4];
  f32x4 O[4];
  float L[4];
  const float QS = 0.25f * 1.44269504088896341f;  // fold scale+log2e into Q
#pragma unroll
  for (int mt = 0; mt < 4; ++mt) {
    int m = mblock * 256 + wave * 64 + mt * 16 + l15;
#pragma unroll
    for (int j = 0; j < 4; ++j)
      qf[mt][j] = (_Float16)(qb[(quad * 4 + j) * 4096 + m] * QS);  // B[c][m]
    O[mt][0] = 0.f; O[mt][1] = 0.f; O[mt][2] = 0.f; O[mt][3] = 0.f;
    L[mt] = 0.f;
  }

#pragma unroll 2
  for (int t = 0; t < 16; ++t) {
    // K frag: A[n][c]: n = t*16 + l15, c = quad*4+j -> one 8B load from kT
    f16x4 kf = *(const f16x4*)(kbT + (t * 16 + l15) * 64 + h * 16 + quad * 4);
    // V frag: A[c][n]: c = l15, n = t*16 + quad*4+j -> contiguous 8B f16x4
    f16x4 vf = *(const f16x4*)(vb + l15 * 256 + t * 16 + quad * 4);

    f32x4 S[4];
#pragma unroll
    for (int mt = 0; mt < 4; ++mt) {
      f32x4 Z = {0.f, 0.f, 0.f, 0.f};
      S[mt] = __builtin_amdgcn_mfma_f32_16x16x16f16(kf, qf[mt], Z, 0, 0, 0);
    }

    f16x4 pf[4];
#pragma unroll
    for (int r = 0; r < 4; ++r) {
      int kidx = t * 16 + quad * 4 + r;
      int off = s_off[kidx];                      // broadcast b32
      f16x4 wt = s_wt[kidx];                      // broadcast b64
      f16x2 wt01; wt01[0] = wt[0]; wt01[1] = wt[1];
      f16x2 wt23; wt23[0] = wt[2]; wt23[1] = wt[3];
      const f16x2* pb = Trow + off;
      // 8 taps from one base, const dword offsets -> 4x ds_read2_b32
      f16x2 a0 = pb[0],   a1 = pb[16],  a2 = pb[32],  a3 = pb[48];
      f16x2 b0 = pb[128], b1 = pb[144], b2 = pb[160], b3 = pb[176];
      float e0 = __builtin_amdgcn_exp2f(__builtin_amdgcn_fdot2(
          a0, wt01, __builtin_amdgcn_fdot2(b0, wt23, S[0][r], false), false));
      float e1 = __builtin_amdgcn_exp2f(__builtin_amdgcn_fdot2(
          a1, wt01, __builtin_amdgcn_fdot2(b1, wt23, S[1][r], false), false));
      float e2 = __builtin_amdgcn_exp2f(__builtin_amdgcn_fdot2(
          a2, wt01, __builtin_amdgcn_fdot2(b2, wt23, S[2][r], false), false));
      float e3 = __builtin_amdgcn_exp2f(__builtin_amdgcn_fdot2(
          a3, wt01, __builtin_amdgcn_fdot2(b3, wt23, S[3][r], false), false));
      L[0] += e0; L[1] += e1; L[2] += e2; L[3] += e3;
      pf[0][r] = (_Float16)e0; pf[1][r] = (_Float16)e1;
      pf[2][r] = (_Float16)e2; pf[3][r] = (_Float16)e3;
    }
#pragma unroll
    for (int mt = 0; mt < 4; ++mt)
      O[mt] = __builtin_amdgcn_mfma_f32_16x16x16f16(vf, pf[mt], O[mt], 0, 0, 0);
  }

#pragma unroll
  for (int mt = 0; mt < 4; ++mt) {
    float Lm = L[mt];
    Lm += __shfl_xor(Lm, 16);
    Lm += __shfl_xor(Lm, 32);
    float rinv = 1.f / Lm;
    int m = mblock * 256 + wave * 64 + mt * 16 + l15;
#pragma unroll
    for (int r = 0; r < 4; ++r)
      qb[(quad * 4 + r) * 4096 + m] = O[mt][r] * rinv;  // in-place over q
  }
}

// ------------------- po conv, out[l][b][64+o][p] += sum_num conv + bias
// og-split 8 (grid 2048, acc[8]); level-2 blocks loop num in {1,2}.
__global__ __launch_bounds__(256) void k_po(
    const float* __restrict__ attn_buf, const float* __restrict__ po_w,
    const float* __restrict__ po_b, float* __restrict__ out) {
  int wg = blockIdx.x;              // l(2)<<10 | og(8)<<7 | b(8)<<4 | tile(16)
  int tile = wg & 15;
  int b = (wg >> 4) & 7;
  int og = (wg >> 7) & 7;
  int l = (wg >> 10) + 1;           // 1 or 2
  int px = tile * 256 + threadIdx.x;
  int nlo = (l == 1) ? 0 : 1;
  int nPasses = (l == 1) ? 1 : 2;

  float acc[8];
#pragma unroll
  for (int o = 0; o < 8; ++o) acc[o] = 0.f;

  for (int s = 0; s < nPasses; ++s) {
    int num = nlo + s;
    const float* abase = attn_buf + (num * 8 + b) * 64 * 4096 + px;
    const float* w = po_w + num * 4096 + og * 512;
#pragma unroll 8
    for (int c = 0; c < 64; ++c) {
      float xv = abase[c * 4096];   // coalesced, 8 in flight
#pragma unroll
      for (int o = 0; o < 8; ++o) acc[o] += w[o * 64 + c] * xv;  // s_loads
    }
  }

  float* ob = out + ((l * 8 + b) * 128 + 64 + og * 8) * 4096 + px;
#pragma unroll
  for (int o = 0; o < 8; ++o) {
    float bias = po_b[nlo * 64 + og * 8 + o];
    if (l == 2) bias += po_b[128 + og * 8 + o];
    ob[o * 4096] += acc[o] + bias;  // plain RMW, no atomics
  }
}

extern "C" void kernel_launch(void* const* d_in, const int* in_sizes, int n_in,
                              void* d_out, int out_size, void* d_ws,
                              size_t ws_size, hipStream_t stream) {
  const float* x0 = (const float*)d_in[0];
  const float* x1 = (const float*)d_in[1];
  const float* x2 = (const float*)d_in[2];
  const float* pq_w = (const float*)d_in[3];
  const float* pq_b = (const float*)d_in[4];
  const float* dw_w = (const float*)d_in[5];
  const float* dw_b = (const float*)d_in[6];
  const float* ln_g = (const float*)d_in[7];
  const float* ln_b = (const float*)d_in[8];
  const float* pw_w = (const float*)d_in[9];
  const float* pk_w = (const float*)d_in[10];
  const float* pk_b = (const float*)d_in[11];
  const float* pv_w = (const float*)d_in[12];
  const float* pv_b = (const float*)d_in[13];
  const float* po_w = (const float*)d_in[14];
  const float* po_b = (const float*)d_in[15];
  const float* rpe = (const float*)d_in[16];
  float* out = (float*)d_out;
  float* ws = (float*)d_ws;

  // ws layout (floats): q/attn (in-place) 6291456, pos 12288, xs 393216,
  // k 393216, v 393216 -> 29,933,568 bytes, IDENTICAL to round-0-proven size.
  // tpad (196608) aliases xs_buf: xs is dead after k_kv; k_padrpe runs after.
  // k holds f16 transposed [nb][256][64] (786KB of the 1.5MB region);
  // v holds f16 [nb][64][256].
  float* q_buf = ws;
  float* pos_buf = q_buf + 6291456;
  float* xs_buf = pos_buf + 12288;
  float* k_buf = xs_buf + 393216;
  float* v_buf = k_buf + 393216;
  float* tpad = xs_buf;
  _Float16* k16 = (_Float16*)k_buf;
  _Float16* v16 = (_Float16*)v_buf;

  hipLaunchKernelGGL(k_copy, dim3(12288), dim3(256), 0, stream, x0, x1, x2, out);
  hipLaunchKernelGGL(k_qconv, dim3(3072), dim3(256), 0, stream, x1, x2, pq_w,
                     pq_b, q_buf);
  hipLaunchKernelGGL(k_offset, dim3(96), dim3(256), 0, stream, q_buf, dw_w,
                     dw_b, ln_g, ln_b, pw_w, pos_buf);
  hipLaunchKernelGGL(k_sample, dim3(384), dim3(256), 0, stream, x0, x1,
                     pos_buf, xs_buf);
  hipLaunchKernelGGL(k_kv, dim3(384), dim3(256), 0, stream, xs_buf, pk_w, pk_b,
                     pv_w, pv_b, k16, v16);
  hipLaunchKernelGGL(k_padrpe, dim3(1536), dim3(128), 0, stream, rpe, tpad);
  hipLaunchKernelGGL(k_attn, dim3(1536), dim3(256), 0, stream, q_buf, k16,
                     v16, pos_buf, tpad);
  hipLaunchKernelGGL(k_po, dim3(2048), dim3(256), 0, stream, q_buf, po_w, po_b,
                     out);
}